// Round 11
// baseline (614.306 us; speedup 1.0000x reference)
//
#include <hip/hip_runtime.h>
#include <math.h>

// AutoLUT forward, MI355X. B=4, N=512, K=3 (PAD=2), Q=16, L=17, UPSCALE=4, SAMPLERS=3.
// R11: stage0 = 256 blocks (1/CU) x 1024 thr, 4 pixels/thread (same (i,j), b=0..3):
//      3 LDS fills per CU total (was 12) and no inter-block serialization.
//      stage1 = R9 form (best measured 162us; L2-gather-bound, VALU tweaks neutral).
static constexpr int B_ = 4;
static constexpr int N_ = 512;
static constexpr int N4_ = 2048;
static constexpr int NPIX = B_ * N_ * N_;      // 2^20
static constexpr int QPIX = NPIX / 4;          // 2^18 per image
static constexpr int LUT_ROWS = 83521;         // 17^4
static constexpr int SPAD = 83584;             // LUT_ROWS padded to 16B multiple
static constexpr int ST0 = 4913, ST1 = 289, ST2 = 17, ST3 = 1;

__device__ __forceinline__ float fixw(float v) {
    v = rintf(v * 127.0f);
    return fminf(fmaxf(v, -127.0f), 127.0f);
}

// (3,83521) -> int8 with 16B-aligned per-sampler stride SPAD
__global__ void fix_lut0_kernel(const float* __restrict__ in, char* __restrict__ out) {
    int t = blockIdx.x * blockDim.x + threadIdx.x;
    int s = blockIdx.y;
    if (t < LUT_ROWS) out[(size_t)s * SPAD + t] = (char)(int)fixw(in[(size_t)s * LUT_ROWS + t]);
}

// (3,83521,16) -> uint8 biased by +127 (range 0..254)
__global__ void fix_lut1_kernel(const float4* __restrict__ in, uchar4* __restrict__ out, int n4) {
    int t = blockIdx.x * blockDim.x + threadIdx.x;
    if (t < n4) {
        float4 v = in[t];
        uchar4 o;
        o.x = (unsigned char)((int)fixw(v.x) + 127);
        o.y = (unsigned char)((int)fixw(v.y) + 127);
        o.z = (unsigned char)((int)fixw(v.z) + 127);
        o.w = (unsigned char)((int)fixw(v.w) + 127);
        out[t] = o;
    }
}

struct Simplex {
    int v[5];
    float w[5];   // pre-scaled by 1/16
};

// 4-D simplex lookup setup. floor/mod by 16 are exact in fp32 (pow-2); sort is a
// stable descending bubble network (ties -> zero-weight vertices, order-irrelevant).
__device__ __forceinline__ Simplex simplex4(float a, float b, float c, float d) {
    float fl0 = floorf(a * 0.0625f), fl1 = floorf(b * 0.0625f),
          fl2 = floorf(c * 0.0625f), fl3 = floorf(d * 0.0625f);
    float f[4] = { a - 16.0f * fl0, b - 16.0f * fl1, c - 16.0f * fl2, d - 16.0f * fl3 };
    int l0 = min(max((int)fl0, 0), 15);
    int l1 = min(max((int)fl1, 0), 15);
    int l2 = min(max((int)fl2, 0), 15);
    int l3 = min(max((int)fl3, 0), 15);
    int st[4] = { ST0, ST1, ST2, ST3 };
#define CSW(A, Bq) { if (f[A] < f[Bq]) { float tf = f[A]; f[A] = f[Bq]; f[Bq] = tf; \
                                         int ts = st[A]; st[A] = st[Bq]; st[Bq] = ts; } }
    CSW(0, 1) CSW(1, 2) CSW(2, 3) CSW(0, 1) CSW(1, 2) CSW(0, 1)
#undef CSW
    Simplex s;
    s.v[0] = l0 * ST0 + l1 * ST1 + l2 * ST2 + l3;
    s.v[1] = s.v[0] + st[0];
    s.v[2] = s.v[1] + st[1];
    s.v[3] = s.v[2] + st[2];
    s.v[4] = s.v[3] + st[3];
    s.w[0] = (16.0f - f[0]) * 0.0625f;
    s.w[1] = (f[0] - f[1]) * 0.0625f;
    s.w[2] = (f[1] - f[2]) * 0.0625f;
    s.w[3] = (f[2] - f[3]) * 0.0625f;
    s.w[4] = f[3] * 0.0625f;
    return s;
}

// Inverse tap map: which (di,dj) of rotation r reads clamped-neighborhood tap (a,c).
// (rotation r + edge-pad + VALID conv + rotate-back == clamped reads, orig frame)
__device__ __forceinline__ bool tap_for_r(int r, int a, int c, int& di, int& dj) {
    if (r == 0) { di = a - 2; dj = c - 2; return (a >= 2) && (c >= 2); }
    if (r == 1) { di = 2 - c; dj = a - 2; return (a >= 2) && (c <= 2); }
    if (r == 2) { di = 2 - a; dj = 2 - c; return (a <= 2) && (c <= 2); }
    di = c - 2; dj = 2 - a; return (a <= 2) && (c >= 2);
}

// unsigned-byte unpack-accumulate: selects v_cvt_f32_ubyte0..3 (1 op/elem)
__device__ __forceinline__ void acc4u(unsigned int q, float wv, float* oc) {
    oc[0] = fmaf(wv, (float)(q & 0xffu), oc[0]);
    oc[1] = fmaf(wv, (float)((q >> 8) & 0xffu), oc[1]);
    oc[2] = fmaf(wv, (float)((q >> 16) & 0xffu), oc[2]);
    oc[3] = fmaf(wv, (float)(q >> 24), oc[3]);
}

__global__ __launch_bounds__(1024, 4) void stage0_kernel(
    const float* __restrict__ x,       // (4,512,512), [0,1]
    const char* __restrict__ lut0q,    // (3,SPAD) int8 fixed, padded stride
    const float* __restrict__ samp0,   // (3,4,3,3)
    const float* __restrict__ sbias0,  // (3,4)
    float* __restrict__ x1)            // out: (4,512,512), integer-valued 0..255
{
    __shared__ char luts[SPAD];        // one sampler's LUT at a time (83.5KB)

    int t = blockIdx.x * blockDim.x + threadIdx.x;   // 0..QPIX-1, same (i,j) all 4 imgs
    int j = t & (N_ - 1);
    int i = t >> 9;

    float pred[4] = {0.0f, 0.0f, 0.0f, 0.0f};

    for (int s = 0; s < 3; ++s) {
        // ---- stage LUT s into LDS (once per sampler per CU)
        __syncthreads();               // previous-iteration readers done
        {
            const int4* src = (const int4*)(lut0q + (size_t)s * SPAD);
            int4* dst = (int4*)luts;
            for (int u = threadIdx.x; u < SPAD / 16; u += 1024) dst[u] = src[u];
        }
        __syncthreads();

        const float* w  = samp0 + s * 36;
        const float* sb = sbias0 + s * 4;

        for (int k = 0; k < 4; ++k) {  // 4 batch images, same (i,j)
            const float* xb = x + (size_t)k * QPIX;

            // tap-outer conv: only 1 pixel + 16 accumulators live
            float vals[4][4];
            #pragma unroll
            for (int r = 0; r < 4; ++r)
                #pragma unroll
                for (int ch = 0; ch < 4; ++ch) vals[r][ch] = 0.0f;
            #pragma unroll
            for (int a = 0; a < 5; ++a) {
                int ri = min(max(i - 2 + a, 0), N_ - 1);
                #pragma unroll
                for (int c = 0; c < 5; ++c) {
                    int ci = min(max(j - 2 + c, 0), N_ - 1);
                    float px = xb[ri * N_ + ci] * 255.0f;
                    #pragma unroll
                    for (int r = 0; r < 4; ++r) {
                        int di, dj;
                        if (tap_for_r(r, a, c, di, dj)) {
                            #pragma unroll
                            for (int ch = 0; ch < 4; ++ch)
                                vals[r][ch] += w[ch * 9 + di * 3 + dj] * px;
                        }
                    }
                }
            }

            // per-rotation: simplex then 5 LDS byte-gathers (small live set)
            float acc = 0.0f;
            #pragma unroll
            for (int r = 0; r < 4; ++r) {
                Simplex sx = simplex4(vals[r][0] + sb[0], vals[r][1] + sb[1],
                                      vals[r][2] + sb[2], vals[r][3] + sb[3]);
                float p0 = (float)luts[sx.v[0]];
                float p1 = (float)luts[sx.v[1]];
                float p2 = (float)luts[sx.v[2]];
                float p3 = (float)luts[sx.v[3]];
                float p4 = (float)luts[sx.v[4]];
                float o = sx.w[0] * p0 + sx.w[1] * p1 + sx.w[2] * p2
                        + sx.w[3] * p3 + sx.w[4] * p4;
                acc = rintf(acc + o);   // ste_round after each rotation
            }
            pred[k] += acc;
        }
    }
    #pragma unroll
    for (int k = 0; k < 4; ++k)
        x1[t + k * QPIX] = rintf(fminf(fmaxf(pred[k] / 12.0f + 127.0f, 0.0f), 255.0f));
}

__global__ __launch_bounds__(256) void stage1_kernel(
    const float* __restrict__ x,        // original (4,512,512), [0,1]
    const float* __restrict__ x1,       // stage-0 out, 0..255
    const unsigned char* __restrict__ lut1q, // (3,83521,16) uint8 = fixw+127
    const float* __restrict__ samp1,    // (3,4,3,3)
    const float* __restrict__ sbias1,   // (3,4)
    const float* __restrict__ resw1,    // (3,2,2)
    float* __restrict__ out)            // (4,2048,2048)
{
    int tid = blockIdx.x * blockDim.x + threadIdx.x;
    if (tid >= NPIX) return;
    int j = tid & (N_ - 1);
    int i = (tid >> 9) & (N_ - 1);
    int b = tid >> 18;
    const float* xb  = x  + (size_t)b * N_ * N_;
    const float* x1b = x1 + (size_t)b * N_ * N_;

    float tot[16];
    #pragma unroll
    for (int k = 0; k < 16; ++k) tot[k] = 0.0f;

    for (int s = 0; s < 3; ++s) {
        const float* w  = samp1 + s * 36;
        const float* sb = sbias1 + s * 4;
        const unsigned char* lut = lut1q + (size_t)s * LUT_ROWS * 16;
        float rw[4];
        #pragma unroll
        for (int ch = 0; ch < 4; ++ch)
            rw[ch] = fminf(fmaxf(resw1[s * 4 + ch], 0.0f), 1.0f);

        // ---- conv phase, then immediately blend so vc/vp die before gathers
        float vals[4][4];
        {
            float vc[4][4], vp[4][4];
            #pragma unroll
            for (int r = 0; r < 4; ++r)
                #pragma unroll
                for (int ch = 0; ch < 4; ++ch) { vc[r][ch] = 0.0f; vp[r][ch] = 0.0f; }
            #pragma unroll
            for (int a = 0; a < 5; ++a) {
                int ri = min(max(i - 2 + a, 0), N_ - 1);
                #pragma unroll
                for (int c = 0; c < 5; ++c) {
                    int ci = min(max(j - 2 + c, 0), N_ - 1);
                    float pc = x1b[ri * N_ + ci];
                    float pp = xb[ri * N_ + ci] * 255.0f;
                    #pragma unroll
                    for (int r = 0; r < 4; ++r) {
                        int di, dj;
                        if (tap_for_r(r, a, c, di, dj)) {
                            #pragma unroll
                            for (int ch = 0; ch < 4; ++ch) {
                                float wt = w[ch * 9 + di * 3 + dj];
                                vc[r][ch] += wt * pc;
                                vp[r][ch] += wt * pp;
                            }
                        }
                    }
                }
            }
            #pragma unroll
            for (int r = 0; r < 4; ++r)
                #pragma unroll
                for (int ch = 0; ch < 4; ++ch)
                    vals[r][ch] = rw[ch] * (vp[r][ch] + sb[ch])
                                + (1.0f - rw[ch]) * (vc[r][ch] + sb[ch]);
        }

        // ---- gather/interp phase
        float acc[16];
        #pragma unroll
        for (int k = 0; k < 16; ++k) acc[k] = 0.0f;

        #pragma unroll
        for (int r = 0; r < 4; ++r) {
            Simplex sx = simplex4(vals[r][0], vals[r][1], vals[r][2], vals[r][3]);
            float oc[16];
            #pragma unroll
            for (int k = 0; k < 16; ++k) oc[k] = 0.0f;
            #pragma unroll
            for (int v = 0; v < 5; ++v) {
                const uint4 q = *(const uint4*)(lut + (size_t)sx.v[v] * 16);
                float wv = sx.w[v];
                acc4u(q.x, wv, oc);
                acc4u(q.y, wv, oc + 4);
                acc4u(q.z, wv, oc + 8);
                acc4u(q.w, wv, oc + 12);
            }
            // remove the +127 bias: sum(ws) == 1 (computed S keeps fp error tiny)
            float S = sx.w[0] + sx.w[1] + sx.w[2] + sx.w[3] + sx.w[4];
            float bias = 127.0f * S;
            #pragma unroll
            for (int k = 0; k < 16; ++k) oc[k] -= bias;
            // scatter rotated 4x4 sub-block into original-orientation accumulator
            #pragma unroll
            for (int u = 0; u < 4; ++u)
                #pragma unroll
                for (int v2 = 0; v2 < 4; ++v2) {
                    int k = 4 * u + v2;
                    int c = (r == 0) ? (4 * u + v2)
                          : (r == 1) ? (4 * (3 - v2) + u)
                          : (r == 2) ? (4 * (3 - u) + (3 - v2))
                                     : (4 * v2 + (3 - u));
                    acc[k] = rintf(acc[k] + oc[c]);   // ste_round per rotation
                }
        }
        #pragma unroll
        for (int k = 0; k < 16; ++k) tot[k] += acc[k];
    }

    float* ob = out + (size_t)b * N4_ * N4_ + (size_t)(i * 4) * N4_ + (j * 4);
    #pragma unroll
    for (int u = 0; u < 4; ++u) {
        float4 val;
        val.x = rintf(fminf(fmaxf(tot[4 * u + 0] / 3.0f, 0.0f), 255.0f)) * (1.0f / 255.0f);
        val.y = rintf(fminf(fmaxf(tot[4 * u + 1] / 3.0f, 0.0f), 255.0f)) * (1.0f / 255.0f);
        val.z = rintf(fminf(fmaxf(tot[4 * u + 2] / 3.0f, 0.0f), 255.0f)) * (1.0f / 255.0f);
        val.w = rintf(fminf(fmaxf(tot[4 * u + 3] / 3.0f, 0.0f), 255.0f)) * (1.0f / 255.0f);
        *(float4*)(ob + (size_t)u * N4_) = val;
    }
}

extern "C" void kernel_launch(void* const* d_in, const int* in_sizes, int n_in,
                              void* d_out, int out_size, void* d_ws, size_t ws_size,
                              hipStream_t stream) {
    const float* x      = (const float*)d_in[0];
    const float* lut0   = (const float*)d_in[1];
    const float* lut1   = (const float*)d_in[2];
    const float* samp0  = (const float*)d_in[3];
    const float* samp1  = (const float*)d_in[4];
    const float* sbias0 = (const float*)d_in[5];
    const float* sbias1 = (const float*)d_in[6];
    const float* resw1  = (const float*)d_in[7];
    float* out = (float*)d_out;
    char* ws   = (char*)d_ws;

    const int N_L1 = 3 * LUT_ROWS * 16;       // 4,009,008
    size_t off_x1 = 0;                        // 4 MB of floats
    size_t off_l0 = (size_t)NPIX * sizeof(float);
    size_t off_l1 = (off_l0 + (size_t)3 * SPAD + 15) & ~(size_t)15;

    float* x1 = (float*)(ws + off_x1);
    char* l0q = ws + off_l0;                  // (3, SPAD) padded
    unsigned char* l1q = (unsigned char*)(ws + off_l1);

    const int threads = 256;

    dim3 g0((LUT_ROWS + threads - 1) / threads, 3);
    fix_lut0_kernel<<<g0, threads, 0, stream>>>(lut0, l0q);
    fix_lut1_kernel<<<(N_L1 / 4 + threads - 1) / threads, threads, 0, stream>>>(
        (const float4*)lut1, (uchar4*)l1q, N_L1 / 4);
    stage0_kernel<<<QPIX / 1024, 1024, 0, stream>>>(x, l0q, samp0, sbias0, x1);
    stage1_kernel<<<NPIX / threads, threads, 0, stream>>>(x, x1, l1q, samp1, sbias1, resw1, out);
}

// Round 12
// 324.198 us; speedup vs baseline: 1.8948x; 1.8948x over previous
//
#include <hip/hip_runtime.h>
#include <math.h>

// AutoLUT forward, MI355X. B=4, N=512, K=3 (PAD=2), Q=16, L=17, UPSCALE=4, SAMPLERS=3.
// R12: stage0 = 512-thread blocks, __launch_bounds__(512,2): LDS (84KB) already caps
//      at 1 block/CU, so the 2-waves/EU hint raises the VGPR cap to 256 and kills the
//      scratch spill that bound stage0 since R7 (R11 counters: VGPR=64, 357MB scratch
//      writes). 1 pixel/thread. stage1 = R9 form (best measured ~162us).
static constexpr int B_ = 4;
static constexpr int N_ = 512;
static constexpr int N4_ = 2048;
static constexpr int NPIX = B_ * N_ * N_;      // 2^20
static constexpr int LUT_ROWS = 83521;         // 17^4
static constexpr int SPAD = 83584;             // LUT_ROWS padded to 16B multiple
static constexpr int ST0 = 4913, ST1 = 289, ST2 = 17, ST3 = 1;

__device__ __forceinline__ float fixw(float v) {
    v = rintf(v * 127.0f);
    return fminf(fmaxf(v, -127.0f), 127.0f);
}

// (3,83521) -> int8 with 16B-aligned per-sampler stride SPAD
__global__ void fix_lut0_kernel(const float* __restrict__ in, char* __restrict__ out) {
    int t = blockIdx.x * blockDim.x + threadIdx.x;
    int s = blockIdx.y;
    if (t < LUT_ROWS) out[(size_t)s * SPAD + t] = (char)(int)fixw(in[(size_t)s * LUT_ROWS + t]);
}

// (3,83521,16) -> uint8 biased by +127 (range 0..254)
__global__ void fix_lut1_kernel(const float4* __restrict__ in, uchar4* __restrict__ out, int n4) {
    int t = blockIdx.x * blockDim.x + threadIdx.x;
    if (t < n4) {
        float4 v = in[t];
        uchar4 o;
        o.x = (unsigned char)((int)fixw(v.x) + 127);
        o.y = (unsigned char)((int)fixw(v.y) + 127);
        o.z = (unsigned char)((int)fixw(v.z) + 127);
        o.w = (unsigned char)((int)fixw(v.w) + 127);
        out[t] = o;
    }
}

struct Simplex {
    int v[5];
    float w[5];   // pre-scaled by 1/16
};

// 4-D simplex lookup setup. floor/mod by 16 are exact in fp32 (pow-2); sort is a
// stable descending bubble network (ties -> zero-weight vertices, order-irrelevant).
__device__ __forceinline__ Simplex simplex4(float a, float b, float c, float d) {
    float fl0 = floorf(a * 0.0625f), fl1 = floorf(b * 0.0625f),
          fl2 = floorf(c * 0.0625f), fl3 = floorf(d * 0.0625f);
    float f[4] = { a - 16.0f * fl0, b - 16.0f * fl1, c - 16.0f * fl2, d - 16.0f * fl3 };
    int l0 = min(max((int)fl0, 0), 15);
    int l1 = min(max((int)fl1, 0), 15);
    int l2 = min(max((int)fl2, 0), 15);
    int l3 = min(max((int)fl3, 0), 15);
    int st[4] = { ST0, ST1, ST2, ST3 };
#define CSW(A, Bq) { if (f[A] < f[Bq]) { float tf = f[A]; f[A] = f[Bq]; f[Bq] = tf; \
                                         int ts = st[A]; st[A] = st[Bq]; st[Bq] = ts; } }
    CSW(0, 1) CSW(1, 2) CSW(2, 3) CSW(0, 1) CSW(1, 2) CSW(0, 1)
#undef CSW
    Simplex s;
    s.v[0] = l0 * ST0 + l1 * ST1 + l2 * ST2 + l3;
    s.v[1] = s.v[0] + st[0];
    s.v[2] = s.v[1] + st[1];
    s.v[3] = s.v[2] + st[2];
    s.v[4] = s.v[3] + st[3];
    s.w[0] = (16.0f - f[0]) * 0.0625f;
    s.w[1] = (f[0] - f[1]) * 0.0625f;
    s.w[2] = (f[1] - f[2]) * 0.0625f;
    s.w[3] = (f[2] - f[3]) * 0.0625f;
    s.w[4] = f[3] * 0.0625f;
    return s;
}

// Inverse tap map: which (di,dj) of rotation r reads clamped-neighborhood tap (a,c).
// (rotation r + edge-pad + VALID conv + rotate-back == clamped reads, orig frame)
__device__ __forceinline__ bool tap_for_r(int r, int a, int c, int& di, int& dj) {
    if (r == 0) { di = a - 2; dj = c - 2; return (a >= 2) && (c >= 2); }
    if (r == 1) { di = 2 - c; dj = a - 2; return (a >= 2) && (c <= 2); }
    if (r == 2) { di = 2 - a; dj = 2 - c; return (a <= 2) && (c <= 2); }
    di = c - 2; dj = 2 - a; return (a <= 2) && (c >= 2);
}

// unsigned-byte unpack-accumulate: selects v_cvt_f32_ubyte0..3 (1 op/elem)
__device__ __forceinline__ void acc4u(unsigned int q, float wv, float* oc) {
    oc[0] = fmaf(wv, (float)(q & 0xffu), oc[0]);
    oc[1] = fmaf(wv, (float)((q >> 8) & 0xffu), oc[1]);
    oc[2] = fmaf(wv, (float)((q >> 16) & 0xffu), oc[2]);
    oc[3] = fmaf(wv, (float)(q >> 24), oc[3]);
}

__global__ __launch_bounds__(512, 2) void stage0_kernel(
    const float* __restrict__ x,       // (4,512,512), [0,1]
    const char* __restrict__ lut0q,    // (3,SPAD) int8 fixed, padded stride
    const float* __restrict__ samp0,   // (3,4,3,3)
    const float* __restrict__ sbias0,  // (3,4)
    float* __restrict__ x1)            // out: (4,512,512), integer-valued 0..255
{
    __shared__ char luts[SPAD];        // one sampler's LUT at a time (83.5KB -> 1 block/CU)

    int tid = blockIdx.x * blockDim.x + threadIdx.x;
    int j = tid & (N_ - 1);
    int i = (tid >> 9) & (N_ - 1);
    int b = tid >> 18;
    const float* xb = x + (size_t)b * N_ * N_;

    float pred = 0.0f;
    for (int s = 0; s < 3; ++s) {
        // ---- stage LUT s into LDS
        __syncthreads();               // previous-iteration readers done
        {
            const int4* src = (const int4*)(lut0q + (size_t)s * SPAD);
            int4* dst = (int4*)luts;
            for (int u = threadIdx.x; u < SPAD / 16; u += 512) dst[u] = src[u];
        }
        __syncthreads();

        const float* w  = samp0 + s * 36;
        const float* sb = sbias0 + s * 4;

        // tap-outer conv: only 1 pixel + 16 accumulators live
        float vals[4][4];
        #pragma unroll
        for (int r = 0; r < 4; ++r)
            #pragma unroll
            for (int ch = 0; ch < 4; ++ch) vals[r][ch] = 0.0f;
        #pragma unroll
        for (int a = 0; a < 5; ++a) {
            int ri = min(max(i - 2 + a, 0), N_ - 1);
            #pragma unroll
            for (int c = 0; c < 5; ++c) {
                int ci = min(max(j - 2 + c, 0), N_ - 1);
                float px = xb[ri * N_ + ci] * 255.0f;
                #pragma unroll
                for (int r = 0; r < 4; ++r) {
                    int di, dj;
                    if (tap_for_r(r, a, c, di, dj)) {
                        #pragma unroll
                        for (int ch = 0; ch < 4; ++ch)
                            vals[r][ch] += w[ch * 9 + di * 3 + dj] * px;
                    }
                }
            }
        }

        // per-rotation: simplex then 5 LDS byte-gathers (small live set)
        float acc = 0.0f;
        #pragma unroll
        for (int r = 0; r < 4; ++r) {
            Simplex sx = simplex4(vals[r][0] + sb[0], vals[r][1] + sb[1],
                                  vals[r][2] + sb[2], vals[r][3] + sb[3]);
            float p0 = (float)luts[sx.v[0]];
            float p1 = (float)luts[sx.v[1]];
            float p2 = (float)luts[sx.v[2]];
            float p3 = (float)luts[sx.v[3]];
            float p4 = (float)luts[sx.v[4]];
            float o = sx.w[0] * p0 + sx.w[1] * p1 + sx.w[2] * p2
                    + sx.w[3] * p3 + sx.w[4] * p4;
            acc = rintf(acc + o);   // ste_round after each rotation
        }
        pred += acc;
    }
    x1[tid] = rintf(fminf(fmaxf(pred / 12.0f + 127.0f, 0.0f), 255.0f));
}

__global__ __launch_bounds__(256) void stage1_kernel(
    const float* __restrict__ x,        // original (4,512,512), [0,1]
    const float* __restrict__ x1,       // stage-0 out, 0..255
    const unsigned char* __restrict__ lut1q, // (3,83521,16) uint8 = fixw+127
    const float* __restrict__ samp1,    // (3,4,3,3)
    const float* __restrict__ sbias1,   // (3,4)
    const float* __restrict__ resw1,    // (3,2,2)
    float* __restrict__ out)            // (4,2048,2048)
{
    int tid = blockIdx.x * blockDim.x + threadIdx.x;
    if (tid >= NPIX) return;
    int j = tid & (N_ - 1);
    int i = (tid >> 9) & (N_ - 1);
    int b = tid >> 18;
    const float* xb  = x  + (size_t)b * N_ * N_;
    const float* x1b = x1 + (size_t)b * N_ * N_;

    float tot[16];
    #pragma unroll
    for (int k = 0; k < 16; ++k) tot[k] = 0.0f;

    for (int s = 0; s < 3; ++s) {
        const float* w  = samp1 + s * 36;
        const float* sb = sbias1 + s * 4;
        const unsigned char* lut = lut1q + (size_t)s * LUT_ROWS * 16;
        float rw[4];
        #pragma unroll
        for (int ch = 0; ch < 4; ++ch)
            rw[ch] = fminf(fmaxf(resw1[s * 4 + ch], 0.0f), 1.0f);

        // ---- conv phase, then immediately blend so vc/vp die before gathers
        float vals[4][4];
        {
            float vc[4][4], vp[4][4];
            #pragma unroll
            for (int r = 0; r < 4; ++r)
                #pragma unroll
                for (int ch = 0; ch < 4; ++ch) { vc[r][ch] = 0.0f; vp[r][ch] = 0.0f; }
            #pragma unroll
            for (int a = 0; a < 5; ++a) {
                int ri = min(max(i - 2 + a, 0), N_ - 1);
                #pragma unroll
                for (int c = 0; c < 5; ++c) {
                    int ci = min(max(j - 2 + c, 0), N_ - 1);
                    float pc = x1b[ri * N_ + ci];
                    float pp = xb[ri * N_ + ci] * 255.0f;
                    #pragma unroll
                    for (int r = 0; r < 4; ++r) {
                        int di, dj;
                        if (tap_for_r(r, a, c, di, dj)) {
                            #pragma unroll
                            for (int ch = 0; ch < 4; ++ch) {
                                float wt = w[ch * 9 + di * 3 + dj];
                                vc[r][ch] += wt * pc;
                                vp[r][ch] += wt * pp;
                            }
                        }
                    }
                }
            }
            #pragma unroll
            for (int r = 0; r < 4; ++r)
                #pragma unroll
                for (int ch = 0; ch < 4; ++ch)
                    vals[r][ch] = rw[ch] * (vp[r][ch] + sb[ch])
                                + (1.0f - rw[ch]) * (vc[r][ch] + sb[ch]);
        }

        // ---- gather/interp phase
        float acc[16];
        #pragma unroll
        for (int k = 0; k < 16; ++k) acc[k] = 0.0f;

        #pragma unroll
        for (int r = 0; r < 4; ++r) {
            Simplex sx = simplex4(vals[r][0], vals[r][1], vals[r][2], vals[r][3]);
            float oc[16];
            #pragma unroll
            for (int k = 0; k < 16; ++k) oc[k] = 0.0f;
            #pragma unroll
            for (int v = 0; v < 5; ++v) {
                const uint4 q = *(const uint4*)(lut + (size_t)sx.v[v] * 16);
                float wv = sx.w[v];
                acc4u(q.x, wv, oc);
                acc4u(q.y, wv, oc + 4);
                acc4u(q.z, wv, oc + 8);
                acc4u(q.w, wv, oc + 12);
            }
            // remove the +127 bias: sum(ws) == 1 (computed S keeps fp error tiny)
            float S = sx.w[0] + sx.w[1] + sx.w[2] + sx.w[3] + sx.w[4];
            float bias = 127.0f * S;
            #pragma unroll
            for (int k = 0; k < 16; ++k) oc[k] -= bias;
            // scatter rotated 4x4 sub-block into original-orientation accumulator
            #pragma unroll
            for (int u = 0; u < 4; ++u)
                #pragma unroll
                for (int v2 = 0; v2 < 4; ++v2) {
                    int k = 4 * u + v2;
                    int c = (r == 0) ? (4 * u + v2)
                          : (r == 1) ? (4 * (3 - v2) + u)
                          : (r == 2) ? (4 * (3 - u) + (3 - v2))
                                     : (4 * v2 + (3 - u));
                    acc[k] = rintf(acc[k] + oc[c]);   // ste_round per rotation
                }
        }
        #pragma unroll
        for (int k = 0; k < 16; ++k) tot[k] += acc[k];
    }

    float* ob = out + (size_t)b * N4_ * N4_ + (size_t)(i * 4) * N4_ + (j * 4);
    #pragma unroll
    for (int u = 0; u < 4; ++u) {
        float4 val;
        val.x = rintf(fminf(fmaxf(tot[4 * u + 0] / 3.0f, 0.0f), 255.0f)) * (1.0f / 255.0f);
        val.y = rintf(fminf(fmaxf(tot[4 * u + 1] / 3.0f, 0.0f), 255.0f)) * (1.0f / 255.0f);
        val.z = rintf(fminf(fmaxf(tot[4 * u + 2] / 3.0f, 0.0f), 255.0f)) * (1.0f / 255.0f);
        val.w = rintf(fminf(fmaxf(tot[4 * u + 3] / 3.0f, 0.0f), 255.0f)) * (1.0f / 255.0f);
        *(float4*)(ob + (size_t)u * N4_) = val;
    }
}

extern "C" void kernel_launch(void* const* d_in, const int* in_sizes, int n_in,
                              void* d_out, int out_size, void* d_ws, size_t ws_size,
                              hipStream_t stream) {
    const float* x      = (const float*)d_in[0];
    const float* lut0   = (const float*)d_in[1];
    const float* lut1   = (const float*)d_in[2];
    const float* samp0  = (const float*)d_in[3];
    const float* samp1  = (const float*)d_in[4];
    const float* sbias0 = (const float*)d_in[5];
    const float* sbias1 = (const float*)d_in[6];
    const float* resw1  = (const float*)d_in[7];
    float* out = (float*)d_out;
    char* ws   = (char*)d_ws;

    const int N_L1 = 3 * LUT_ROWS * 16;       // 4,009,008
    size_t off_x1 = 0;                        // 4 MB of floats
    size_t off_l0 = (size_t)NPIX * sizeof(float);
    size_t off_l1 = (off_l0 + (size_t)3 * SPAD + 15) & ~(size_t)15;

    float* x1 = (float*)(ws + off_x1);
    char* l0q = ws + off_l0;                  // (3, SPAD) padded
    unsigned char* l1q = (unsigned char*)(ws + off_l1);

    const int threads = 256;

    dim3 g0((LUT_ROWS + threads - 1) / threads, 3);
    fix_lut0_kernel<<<g0, threads, 0, stream>>>(lut0, l0q);
    fix_lut1_kernel<<<(N_L1 / 4 + threads - 1) / threads, threads, 0, stream>>>(
        (const float4*)lut1, (uchar4*)l1q, N_L1 / 4);
    stage0_kernel<<<NPIX / 512, 512, 0, stream>>>(x, l0q, samp0, sbias0, x1);
    stage1_kernel<<<NPIX / threads, threads, 0, stream>>>(x, x1, l1q, samp1, sbias1, resw1, out);
}

// Round 13
// 296.662 us; speedup vs baseline: 2.0707x; 1.0928x over previous
//
#include <hip/hip_runtime.h>
#include <math.h>

// AutoLUT forward, MI355X. B=4, N=512, K=3 (PAD=2), Q=16, L=17, UPSCALE=4, SAMPLERS=3.
// R13: 2D-tiled thread->pixel mapping (wave = 16x4 / 32x2 pixel patch instead of 64x1)
//      to raise LUT-gather line sharing within a wave (less TA + L2->L1 traffic).
//      stage0 = R8 config (1024 thr, lb(1024,4), per-rotation gathers, LDS LUT).
//      stage1 = R9 math (uint8+127 LUT, v_cvt_f32_ubyte unpack).
static constexpr int B_ = 4;
static constexpr int N_ = 512;
static constexpr int N4_ = 2048;
static constexpr int NPIX = B_ * N_ * N_;      // 2^20
static constexpr int LUT_ROWS = 83521;         // 17^4
static constexpr int SPAD = 83584;             // LUT_ROWS padded to 16B multiple
static constexpr int ST0 = 4913, ST1 = 289, ST2 = 17, ST3 = 1;

__device__ __forceinline__ float fixw(float v) {
    v = rintf(v * 127.0f);
    return fminf(fmaxf(v, -127.0f), 127.0f);
}

// (3,83521) -> int8 with 16B-aligned per-sampler stride SPAD
__global__ void fix_lut0_kernel(const float* __restrict__ in, char* __restrict__ out) {
    int t = blockIdx.x * blockDim.x + threadIdx.x;
    int s = blockIdx.y;
    if (t < LUT_ROWS) out[(size_t)s * SPAD + t] = (char)(int)fixw(in[(size_t)s * LUT_ROWS + t]);
}

// (3,83521,16) -> uint8 biased by +127 (range 0..254)
__global__ void fix_lut1_kernel(const float4* __restrict__ in, uchar4* __restrict__ out, int n4) {
    int t = blockIdx.x * blockDim.x + threadIdx.x;
    if (t < n4) {
        float4 v = in[t];
        uchar4 o;
        o.x = (unsigned char)((int)fixw(v.x) + 127);
        o.y = (unsigned char)((int)fixw(v.y) + 127);
        o.z = (unsigned char)((int)fixw(v.z) + 127);
        o.w = (unsigned char)((int)fixw(v.w) + 127);
        out[t] = o;
    }
}

struct Simplex {
    int v[5];
    float w[5];   // pre-scaled by 1/16
};

// 4-D simplex lookup setup. floor/mod by 16 are exact in fp32 (pow-2); sort is a
// stable descending bubble network (ties -> zero-weight vertices, order-irrelevant).
__device__ __forceinline__ Simplex simplex4(float a, float b, float c, float d) {
    float fl0 = floorf(a * 0.0625f), fl1 = floorf(b * 0.0625f),
          fl2 = floorf(c * 0.0625f), fl3 = floorf(d * 0.0625f);
    float f[4] = { a - 16.0f * fl0, b - 16.0f * fl1, c - 16.0f * fl2, d - 16.0f * fl3 };
    int l0 = min(max((int)fl0, 0), 15);
    int l1 = min(max((int)fl1, 0), 15);
    int l2 = min(max((int)fl2, 0), 15);
    int l3 = min(max((int)fl3, 0), 15);
    int st[4] = { ST0, ST1, ST2, ST3 };
#define CSW(A, Bq) { if (f[A] < f[Bq]) { float tf = f[A]; f[A] = f[Bq]; f[Bq] = tf; \
                                         int ts = st[A]; st[A] = st[Bq]; st[Bq] = ts; } }
    CSW(0, 1) CSW(1, 2) CSW(2, 3) CSW(0, 1) CSW(1, 2) CSW(0, 1)
#undef CSW
    Simplex s;
    s.v[0] = l0 * ST0 + l1 * ST1 + l2 * ST2 + l3;
    s.v[1] = s.v[0] + st[0];
    s.v[2] = s.v[1] + st[1];
    s.v[3] = s.v[2] + st[2];
    s.v[4] = s.v[3] + st[3];
    s.w[0] = (16.0f - f[0]) * 0.0625f;
    s.w[1] = (f[0] - f[1]) * 0.0625f;
    s.w[2] = (f[1] - f[2]) * 0.0625f;
    s.w[3] = (f[2] - f[3]) * 0.0625f;
    s.w[4] = f[3] * 0.0625f;
    return s;
}

// Inverse tap map: which (di,dj) of rotation r reads clamped-neighborhood tap (a,c).
// (rotation r + edge-pad + VALID conv + rotate-back == clamped reads, orig frame)
__device__ __forceinline__ bool tap_for_r(int r, int a, int c, int& di, int& dj) {
    if (r == 0) { di = a - 2; dj = c - 2; return (a >= 2) && (c >= 2); }
    if (r == 1) { di = 2 - c; dj = a - 2; return (a >= 2) && (c <= 2); }
    if (r == 2) { di = 2 - a; dj = 2 - c; return (a <= 2) && (c <= 2); }
    di = c - 2; dj = 2 - a; return (a <= 2) && (c >= 2);
}

// unsigned-byte unpack-accumulate: selects v_cvt_f32_ubyte0..3 (1 op/elem)
__device__ __forceinline__ void acc4u(unsigned int q, float wv, float* oc) {
    oc[0] = fmaf(wv, (float)(q & 0xffu), oc[0]);
    oc[1] = fmaf(wv, (float)((q >> 8) & 0xffu), oc[1]);
    oc[2] = fmaf(wv, (float)((q >> 16) & 0xffu), oc[2]);
    oc[3] = fmaf(wv, (float)(q >> 24), oc[3]);
}

__global__ __launch_bounds__(1024, 4) void stage0_kernel(
    const float* __restrict__ x,       // (4,512,512), [0,1]
    const char* __restrict__ lut0q,    // (3,SPAD) int8 fixed, padded stride
    const float* __restrict__ samp0,   // (3,4,3,3)
    const float* __restrict__ sbias0,  // (3,4)
    float* __restrict__ x1)            // out: (4,512,512), integer-valued 0..255
{
    __shared__ char luts[SPAD];        // one sampler's LUT at a time (83.5KB -> 1 blk/CU)

    // 32x32 pixel tile per block; wave = 32x2 patch (tighter than 64x1)
    int b    = blockIdx.x >> 8;
    int tile = blockIdx.x & 255;
    int i = ((tile >> 4) << 5) + (threadIdx.x >> 5);
    int j = ((tile & 15) << 5) + (threadIdx.x & 31);
    const float* xb = x + (size_t)b * N_ * N_;

    float pred = 0.0f;
    for (int s = 0; s < 3; ++s) {
        // ---- stage LUT s into LDS
        __syncthreads();               // previous-iteration readers done
        {
            const int4* src = (const int4*)(lut0q + (size_t)s * SPAD);
            int4* dst = (int4*)luts;
            for (int u = threadIdx.x; u < SPAD / 16; u += 1024) dst[u] = src[u];
        }
        __syncthreads();

        const float* w  = samp0 + s * 36;
        const float* sb = sbias0 + s * 4;

        // tap-outer conv: only 1 pixel + 16 accumulators live
        float vals[4][4];
        #pragma unroll
        for (int r = 0; r < 4; ++r)
            #pragma unroll
            for (int ch = 0; ch < 4; ++ch) vals[r][ch] = 0.0f;
        #pragma unroll
        for (int a = 0; a < 5; ++a) {
            int ri = min(max(i - 2 + a, 0), N_ - 1);
            #pragma unroll
            for (int c = 0; c < 5; ++c) {
                int ci = min(max(j - 2 + c, 0), N_ - 1);
                float px = xb[ri * N_ + ci] * 255.0f;
                #pragma unroll
                for (int r = 0; r < 4; ++r) {
                    int di, dj;
                    if (tap_for_r(r, a, c, di, dj)) {
                        #pragma unroll
                        for (int ch = 0; ch < 4; ++ch)
                            vals[r][ch] += w[ch * 9 + di * 3 + dj] * px;
                    }
                }
            }
        }

        // per-rotation: simplex then 5 LDS byte-gathers (small live set)
        float acc = 0.0f;
        #pragma unroll
        for (int r = 0; r < 4; ++r) {
            Simplex sx = simplex4(vals[r][0] + sb[0], vals[r][1] + sb[1],
                                  vals[r][2] + sb[2], vals[r][3] + sb[3]);
            float p0 = (float)luts[sx.v[0]];
            float p1 = (float)luts[sx.v[1]];
            float p2 = (float)luts[sx.v[2]];
            float p3 = (float)luts[sx.v[3]];
            float p4 = (float)luts[sx.v[4]];
            float o = sx.w[0] * p0 + sx.w[1] * p1 + sx.w[2] * p2
                    + sx.w[3] * p3 + sx.w[4] * p4;
            acc = rintf(acc + o);   // ste_round after each rotation
        }
        pred += acc;
    }
    x1[(size_t)b * N_ * N_ + i * N_ + j] =
        rintf(fminf(fmaxf(pred / 12.0f + 127.0f, 0.0f), 255.0f));
}

__global__ __launch_bounds__(256) void stage1_kernel(
    const float* __restrict__ x,        // original (4,512,512), [0,1]
    const float* __restrict__ x1,       // stage-0 out, 0..255
    const unsigned char* __restrict__ lut1q, // (3,83521,16) uint8 = fixw+127
    const float* __restrict__ samp1,    // (3,4,3,3)
    const float* __restrict__ sbias1,   // (3,4)
    const float* __restrict__ resw1,    // (3,2,2)
    float* __restrict__ out)            // (4,2048,2048)
{
    // 16x16 pixel tile per block; wave = 16x4 patch (tighter than 64x1)
    int b    = blockIdx.x >> 10;
    int tile = blockIdx.x & 1023;
    int i = ((tile >> 5) << 4) + (threadIdx.x >> 4);
    int j = ((tile & 31) << 4) + (threadIdx.x & 15);
    const float* xb  = x  + (size_t)b * N_ * N_;
    const float* x1b = x1 + (size_t)b * N_ * N_;

    float tot[16];
    #pragma unroll
    for (int k = 0; k < 16; ++k) tot[k] = 0.0f;

    for (int s = 0; s < 3; ++s) {
        const float* w  = samp1 + s * 36;
        const float* sb = sbias1 + s * 4;
        const unsigned char* lut = lut1q + (size_t)s * LUT_ROWS * 16;
        float rw[4];
        #pragma unroll
        for (int ch = 0; ch < 4; ++ch)
            rw[ch] = fminf(fmaxf(resw1[s * 4 + ch], 0.0f), 1.0f);

        // ---- conv phase, then immediately blend so vc/vp die before gathers
        float vals[4][4];
        {
            float vc[4][4], vp[4][4];
            #pragma unroll
            for (int r = 0; r < 4; ++r)
                #pragma unroll
                for (int ch = 0; ch < 4; ++ch) { vc[r][ch] = 0.0f; vp[r][ch] = 0.0f; }
            #pragma unroll
            for (int a = 0; a < 5; ++a) {
                int ri = min(max(i - 2 + a, 0), N_ - 1);
                #pragma unroll
                for (int c = 0; c < 5; ++c) {
                    int ci = min(max(j - 2 + c, 0), N_ - 1);
                    float pc = x1b[ri * N_ + ci];
                    float pp = xb[ri * N_ + ci] * 255.0f;
                    #pragma unroll
                    for (int r = 0; r < 4; ++r) {
                        int di, dj;
                        if (tap_for_r(r, a, c, di, dj)) {
                            #pragma unroll
                            for (int ch = 0; ch < 4; ++ch) {
                                float wt = w[ch * 9 + di * 3 + dj];
                                vc[r][ch] += wt * pc;
                                vp[r][ch] += wt * pp;
                            }
                        }
                    }
                }
            }
            #pragma unroll
            for (int r = 0; r < 4; ++r)
                #pragma unroll
                for (int ch = 0; ch < 4; ++ch)
                    vals[r][ch] = rw[ch] * (vp[r][ch] + sb[ch])
                                + (1.0f - rw[ch]) * (vc[r][ch] + sb[ch]);
        }

        // ---- gather/interp phase
        float acc[16];
        #pragma unroll
        for (int k = 0; k < 16; ++k) acc[k] = 0.0f;

        #pragma unroll
        for (int r = 0; r < 4; ++r) {
            Simplex sx = simplex4(vals[r][0], vals[r][1], vals[r][2], vals[r][3]);
            float oc[16];
            #pragma unroll
            for (int k = 0; k < 16; ++k) oc[k] = 0.0f;
            #pragma unroll
            for (int v = 0; v < 5; ++v) {
                const uint4 q = *(const uint4*)(lut + (size_t)sx.v[v] * 16);
                float wv = sx.w[v];
                acc4u(q.x, wv, oc);
                acc4u(q.y, wv, oc + 4);
                acc4u(q.z, wv, oc + 8);
                acc4u(q.w, wv, oc + 12);
            }
            // remove the +127 bias: sum(ws) == 1 (computed S keeps fp error tiny)
            float S = sx.w[0] + sx.w[1] + sx.w[2] + sx.w[3] + sx.w[4];
            float bias = 127.0f * S;
            #pragma unroll
            for (int k = 0; k < 16; ++k) oc[k] -= bias;
            // scatter rotated 4x4 sub-block into original-orientation accumulator
            #pragma unroll
            for (int u = 0; u < 4; ++u)
                #pragma unroll
                for (int v2 = 0; v2 < 4; ++v2) {
                    int k = 4 * u + v2;
                    int c = (r == 0) ? (4 * u + v2)
                          : (r == 1) ? (4 * (3 - v2) + u)
                          : (r == 2) ? (4 * (3 - u) + (3 - v2))
                                     : (4 * v2 + (3 - u));
                    acc[k] = rintf(acc[k] + oc[c]);   // ste_round per rotation
                }
        }
        #pragma unroll
        for (int k = 0; k < 16; ++k) tot[k] += acc[k];
    }

    float* ob = out + (size_t)b * N4_ * N4_ + (size_t)(i * 4) * N4_ + (j * 4);
    #pragma unroll
    for (int u = 0; u < 4; ++u) {
        float4 val;
        val.x = rintf(fminf(fmaxf(tot[4 * u + 0] / 3.0f, 0.0f), 255.0f)) * (1.0f / 255.0f);
        val.y = rintf(fminf(fmaxf(tot[4 * u + 1] / 3.0f, 0.0f), 255.0f)) * (1.0f / 255.0f);
        val.z = rintf(fminf(fmaxf(tot[4 * u + 2] / 3.0f, 0.0f), 255.0f)) * (1.0f / 255.0f);
        val.w = rintf(fminf(fmaxf(tot[4 * u + 3] / 3.0f, 0.0f), 255.0f)) * (1.0f / 255.0f);
        *(float4*)(ob + (size_t)u * N4_) = val;
    }
}

extern "C" void kernel_launch(void* const* d_in, const int* in_sizes, int n_in,
                              void* d_out, int out_size, void* d_ws, size_t ws_size,
                              hipStream_t stream) {
    const float* x      = (const float*)d_in[0];
    const float* lut0   = (const float*)d_in[1];
    const float* lut1   = (const float*)d_in[2];
    const float* samp0  = (const float*)d_in[3];
    const float* samp1  = (const float*)d_in[4];
    const float* sbias0 = (const float*)d_in[5];
    const float* sbias1 = (const float*)d_in[6];
    const float* resw1  = (const float*)d_in[7];
    float* out = (float*)d_out;
    char* ws   = (char*)d_ws;

    const int N_L1 = 3 * LUT_ROWS * 16;       // 4,009,008
    size_t off_x1 = 0;                        // 4 MB of floats
    size_t off_l0 = (size_t)NPIX * sizeof(float);
    size_t off_l1 = (off_l0 + (size_t)3 * SPAD + 15) & ~(size_t)15;

    float* x1 = (float*)(ws + off_x1);
    char* l0q = ws + off_l0;                  // (3, SPAD) padded
    unsigned char* l1q = (unsigned char*)(ws + off_l1);

    const int threads = 256;

    dim3 g0((LUT_ROWS + threads - 1) / threads, 3);
    fix_lut0_kernel<<<g0, threads, 0, stream>>>(lut0, l0q);
    fix_lut1_kernel<<<(N_L1 / 4 + threads - 1) / threads, threads, 0, stream>>>(
        (const float4*)lut1, (uchar4*)l1q, N_L1 / 4);
    stage0_kernel<<<NPIX / 1024, 1024, 0, stream>>>(x, l0q, samp0, sbias0, x1);
    stage1_kernel<<<NPIX / threads, threads, 0, stream>>>(x, x1, l1q, samp1, sbias1, resw1, out);
}